// Round 4
// baseline (10854.214 us; speedup 1.0000x reference)
//
#include <hip/hip_runtime.h>
#include <hip/hip_bf16.h>
#include <stdint.h>
#include <math.h>

#define NB 128
#define NN 200
#define ND 128
#define NH 8
#define DH 16
#define NL 3
#define NF 2048
#define NT (NB * NN)
#define NSTEP 399
#define RNG_PARTITIONABLE 1

// ---------------- Threefry-2x32 (JAX-compatible) ----------------
__host__ __device__ inline void tf2x32(unsigned k0, unsigned k1, unsigned x0, unsigned x1,
                                       unsigned* o0, unsigned* o1) {
  unsigned ks[3] = {k0, k1, k0 ^ k1 ^ 0x1BD11BDAu};
  x0 += ks[0]; x1 += ks[1];
  const unsigned R[2][4] = {{13u, 15u, 26u, 6u}, {17u, 29u, 16u, 24u}};
#pragma unroll
  for (int i = 0; i < 5; ++i) {
#pragma unroll
    for (int j = 0; j < 4; ++j) {
      unsigned r = R[i & 1][j];
      x0 += x1;
      x1 = (x1 << r) | (x1 >> (32u - r));
      x1 ^= x0;
    }
    x0 += ks[(i + 1) % 3];
    x1 += ks[(i + 2) % 3] + (unsigned)(i + 1);
  }
  *o0 = x0; *o1 = x1;
}

// per-step subkeys for the scan's key chain, computed on device (1 thread)
__global__ void k_rng(unsigned* __restrict__ rng) {
  unsigned k0 = 0u, k1 = 42u;
  for (int t = 0; t < NSTEP; ++t) {
#if RNG_PARTITIONABLE
    unsigned a0, a1, s0, s1;
    tf2x32(k0, k1, 0u, 1u, &s0, &s1);  // sk  = keys[1]
    tf2x32(k0, k1, 0u, 0u, &a0, &a1);  // key' = keys[0]
    rng[2 * t] = s0; rng[2 * t + 1] = s1;
    k0 = a0; k1 = a1;
#else
    unsigned a0, a1, b0_, b1_;
    tf2x32(k0, k1, 0u, 2u, &a0, &a1);
    tf2x32(k0, k1, 1u, 3u, &b0_, &b1_);
    rng[2 * t] = a1; rng[2 * t + 1] = b1_;  // sk = keys[1] = (o1(0,2), o1(1,3))
    k0 = a0; k1 = b0_;                      // key' = keys[0]
#endif
  }
}

// ---------------- embed: h = [coords, dr] @ Wt + b ----------------
__global__ void k_embed(const float* __restrict__ coords, const float* __restrict__ dem,
                        const float* __restrict__ cap, const float* __restrict__ eW,
                        const float* __restrict__ eb, float* __restrict__ h, float* __restrict__ dr) {
  int gid = blockIdx.x * blockDim.x + threadIdx.x;
  int t = gid >> 7, d = gid & 127;
  int b = t / NN;
  float drv = dem[t] / cap[b];
  double acc = (double)eW[d * 3] * (double)coords[2 * t]
             + (double)eW[d * 3 + 1] * (double)coords[2 * t + 1]
             + (double)eW[d * 3 + 2] * (double)drv;
  h[gid] = (float)acc + eb[d];
  if (d == 0) dr[t] = drv;
}

// ---------------- qkv = h @ Wqkv^T + b  (block per token, 384 outputs) ----------------
__global__ __launch_bounds__(384) void k_qkv(const float* __restrict__ h, const float* __restrict__ W,
                                             const float* __restrict__ bias, float* __restrict__ qkv) {
  const int t = blockIdx.x, j = threadIdx.x;
  __shared__ float hrow[ND];
  if (j < ND) hrow[j] = h[(size_t)t * ND + j];
  __syncthreads();
  double acc = 0.0;
  const float* wr = W + (size_t)j * ND;
  for (int k = 0; k < ND; ++k) acc += (double)hrow[k] * (double)wr[k];
  qkv[(size_t)t * 384 + j] = (float)acc + bias[j];
}

// ---------------- attention (block per (b,head)) ----------------
__global__ __launch_bounds__(256) void k_attn(const float* __restrict__ qkv, float* __restrict__ att) {
  const int b = blockIdx.x / NH, hh = blockIdx.x % NH, tid = threadIdx.x;
  const int lane = tid & 63, w = tid >> 6;
  __shared__ float ksh[NN][DH + 1];
  __shared__ float vsh[NN][DH + 1];
  __shared__ float ash[NN];
  __shared__ float qsh[DH];
  __shared__ float redf[4];
  __shared__ double redd[4];
  __shared__ double pp[16][DH + 1];
  __shared__ float s_m;
  __shared__ double s_sum;
  for (int idx = tid; idx < NN * DH; idx += 256) {
    int n = idx / DH, d2 = idx % DH;
    size_t base = (size_t)(b * NN + n) * 384 + hh * DH + d2;
    ksh[n][d2] = qkv[base + ND];
    vsh[n][d2] = qkv[base + 2 * ND];
  }
  __syncthreads();
  for (int qn = 0; qn < NN; ++qn) {
    if (tid < DH) qsh[tid] = qkv[(size_t)(b * NN + qn) * 384 + hh * DH + tid];
    __syncthreads();
    float s = -3.0e38f;
    if (tid < NN) {
      double acc = 0.0;
#pragma unroll
      for (int d2 = 0; d2 < DH; ++d2) acc += (double)qsh[d2] * (double)ksh[tid][d2];
      s = (float)acc / 4.0f;  // / sqrt(dh)
    }
    float mv = s;
    for (int off = 32; off; off >>= 1) mv = fmaxf(mv, __shfl_down(mv, off, 64));
    if (lane == 0) redf[w] = mv;
    __syncthreads();
    if (tid == 0) s_m = fmaxf(fmaxf(redf[0], redf[1]), fmaxf(redf[2], redf[3]));
    __syncthreads();
    float m = s_m;
    double e = 0.0;
    if (tid < NN) e = exp((double)(s - m));
    double ev = e;
    for (int off = 32; off; off >>= 1) ev += __shfl_down(ev, off, 64);
    if (lane == 0) redd[w] = ev;
    __syncthreads();
    if (tid == 0) s_sum = redd[0] + redd[1] + redd[2] + redd[3];
    __syncthreads();
    if (tid < NN) ash[tid] = (float)(e / s_sum);
    __syncthreads();
    {
      int c = tid >> 4, d2 = tid & 15;
      double acc = 0.0;
      for (int n = c; n < NN; n += 16) acc += (double)ash[n] * (double)vsh[n][d2];
      pp[c][d2] = acc;
    }
    __syncthreads();
    if (tid < DH) {
      double o = 0.0;
#pragma unroll
      for (int c = 0; c < 16; ++c) o += pp[c][tid];
      att[(size_t)(b * NN + qn) * ND + hh * DH + tid] = (float)o;
    }
    __syncthreads();
  }
}

// ---------------- o-proj + residual + LN1 (block per token) ----------------
__global__ __launch_bounds__(128) void k_oln(const float* __restrict__ att, const float* __restrict__ Wo,
                                             const float* __restrict__ bo, const float* __restrict__ g,
                                             const float* __restrict__ bb, float* __restrict__ h) {
  const int t = blockIdx.x, d = threadIdx.x;
  const int lane = d & 63, w = d >> 6;
  __shared__ float orow[ND];
  __shared__ double red[2];
  __shared__ float s_m, s_s;
  orow[d] = att[(size_t)t * ND + d];
  __syncthreads();
  double acc = 0.0;
  const float* wr = Wo + (size_t)d * ND;
  for (int k = 0; k < ND; ++k) acc += (double)orow[k] * (double)wr[k];
  float o = (float)acc + bo[d];
  float x = h[(size_t)t * ND + d] + o;
  double sv = x;
  for (int off = 32; off; off >>= 1) sv += __shfl_down(sv, off, 64);
  if (lane == 0) red[w] = sv;
  __syncthreads();
  if (d == 0) s_m = (float)((red[0] + red[1]) / 128.0);
  __syncthreads();
  float m = s_m;
  float tf = x - m;
  double sq = (double)tf * (double)tf;
  for (int off = 32; off; off >>= 1) sq += __shfl_down(sq, off, 64);
  if (lane == 0) red[w] = sq;
  __syncthreads();
  if (d == 0) s_s = sqrtf((float)((red[0] + red[1]) / 128.0) + 1e-5f);
  __syncthreads();
  float y = tf / s_s;
  h[(size_t)t * ND + d] = y * g[d] + bb[d];
}

// ---------------- FFN + residual + LN2 (block per 4 tokens) ----------------
#define FT 4
__global__ __launch_bounds__(256) void k_ffn(float* __restrict__ h, const float* __restrict__ W1,
                                             const float* __restrict__ b1, const float* __restrict__ W2,
                                             const float* __restrict__ b2, const float* __restrict__ g,
                                             const float* __restrict__ bb) {
  const int t0 = blockIdx.x * FT, tid = threadIdx.x;
  __shared__ float hsh[FT][ND + 4];
  __shared__ float fsh[FT][NF + 4];
  __shared__ float xsh[FT][ND + 4];
  __shared__ float mred[FT], sred[FT];
  for (int idx = tid; idx < FT * ND; idx += 256)
    hsh[idx / ND][idx % ND] = h[(size_t)(t0 + idx / ND) * ND + (idx % ND)];
  __syncthreads();
  for (int rep = 0; rep < (FT * NF) / 256; ++rep) {
    int lin = rep * 256 + tid;
    int j = lin >> 2, tt = lin & 3;
    double acc = 0.0;
    const float* wr = W1 + (size_t)j * ND;
    for (int k = 0; k < ND; ++k) acc += (double)hsh[tt][k] * (double)wr[k];
    float f = (float)acc + b1[j];
    fsh[tt][j] = fmaxf(f, 0.0f);
  }
  __syncthreads();
  for (int rep = 0; rep < (FT * ND) / 256; ++rep) {
    int lin = rep * 256 + tid;
    int d = lin >> 2, tt = lin & 3;
    double acc = 0.0;
    const float* wr = W2 + (size_t)d * NF;
    for (int j = 0; j < NF; ++j) acc += (double)fsh[tt][j] * (double)wr[j];
    float o = (float)acc + b2[d];
    xsh[tt][d] = hsh[tt][d] + o;
  }
  __syncthreads();
  if (tid < FT) {
    double sv = 0.0;
    for (int d = 0; d < ND; ++d) sv += (double)xsh[tid][d];
    float m = (float)(sv / 128.0);
    double sq = 0.0;
    for (int d = 0; d < ND; ++d) { float tf = xsh[tid][d] - m; sq += (double)tf * (double)tf; }
    mred[tid] = m;
    sred[tid] = sqrtf((float)(sq / 128.0) + 1e-5f);
  }
  __syncthreads();
  for (int rep = 0; rep < (FT * ND) / 256; ++rep) {
    int lin = rep * 256 + tid;
    int d = lin >> 2, tt = lin & 3;
    float tf = xsh[tt][d] - mred[tt];
    float y = tf / sred[tt];
    h[(size_t)(t0 + tt) * ND + d] = y * g[d] + bb[d];
  }
}

// ---------------- decode precompute ----------------
__global__ __launch_bounds__(128) void k_gctx(const float* __restrict__ h, float* __restrict__ gctx) {
  int b = blockIdx.x, d = threadIdx.x;
  double acc = 0.0;
  for (int n = 0; n < NN; ++n) acc += (double)h[(size_t)(b * NN + n) * ND + d];
  gctx[b * ND + d] = (float)(acc / 200.0);
}

__global__ __launch_bounds__(128) void k_kmat(const float* __restrict__ h, const float* __restrict__ Wk,
                                              float* __restrict__ kmat) {
  int t = blockIdx.x, d = threadIdx.x;
  __shared__ float hrow[ND];
  hrow[d] = h[(size_t)t * ND + d];
  __syncthreads();
  double acc = 0.0;
  const float* wr = Wk + (size_t)d * ND;
  for (int k = 0; k < ND; ++k) acc += (double)hrow[k] * (double)wr[k];
  kmat[(size_t)t * ND + d] = (float)acc;
}

// t1[k] = sum_m Wctx[k][256+m]*bcap[m] + bctx[k]; wu[k] = sum_m Wctx[k][256+m]*Wcap[m]
__global__ __launch_bounds__(128) void k_prep1(const float* __restrict__ Wctx, const float* __restrict__ bcap,
                                               const float* __restrict__ Wcap, const float* __restrict__ bctx,
                                               double* __restrict__ t1, double* __restrict__ wu) {
  int k = threadIdx.x;
  double a = 0.0, c = 0.0;
  for (int m = 0; m < ND; ++m) {
    double wc = (double)Wctx[(size_t)k * 384 + 256 + m];
    a += wc * (double)bcap[m];
    c += wc * (double)Wcap[m];
  }
  t1[k] = a + (double)bctx[k];
  wu[k] = c;
}

// M[d][j] = sum_k Wq[d][k]*Wctx[k][j]
__global__ __launch_bounds__(128) void k_M(const float* __restrict__ Wq, const float* __restrict__ Wctx,
                                           double* __restrict__ M) {
  int d = blockIdx.x, j = threadIdx.x;
  double acc = 0.0;
  for (int k = 0; k < ND; ++k)
    acc += (double)Wq[(size_t)d * ND + k] * (double)Wctx[(size_t)k * 384 + j];
  M[(size_t)d * ND + j] = acc;
}

__global__ __launch_bounds__(128) void k_u(const float* __restrict__ Wq, const double* __restrict__ wu,
                                           double* __restrict__ u) {
  int d = threadIdx.x;
  double acc = 0.0;
  for (int k = 0; k < ND; ++k) acc += (double)Wq[(size_t)d * ND + k] * wu[k];
  u[d] = acc;
}

// t2[b][k] = sum_m Wctx[k][128+m]*gctx[b][m]
__global__ __launch_bounds__(128) void k_t2(const float* __restrict__ Wctx, const float* __restrict__ gctx,
                                            double* __restrict__ t2) {
  int b = blockIdx.x, k = threadIdx.x;
  double acc = 0.0;
  for (int m = 0; m < ND; ++m)
    acc += (double)Wctx[(size_t)k * 384 + 128 + m] * (double)gctx[b * ND + m];
  t2[(size_t)b * ND + k] = acc;
}

// vb[b][d] = sum_k Wq[d][k]*(t2[b][k]+t1[k])
__global__ __launch_bounds__(128) void k_vb(const float* __restrict__ Wq, const double* __restrict__ t2,
                                            const double* __restrict__ t1, double* __restrict__ vb) {
  int b = blockIdx.x, d = threadIdx.x;
  double acc = 0.0;
  for (int k = 0; k < ND; ++k)
    acc += (double)Wq[(size_t)d * ND + k] * (t2[(size_t)b * ND + k] + t1[k]);
  vb[(size_t)b * ND + d] = acc;
}

__global__ __launch_bounds__(256) void k_c01(const float* __restrict__ kmat, const double* __restrict__ vb,
                                             const double* __restrict__ u, float* __restrict__ c0, float* __restrict__ c1) {
  int t = blockIdx.x * 256 + threadIdx.x;
  if (t >= NT) return;
  int b = t / NN;
  double a0 = 0.0, a1 = 0.0;
  for (int d = 0; d < ND; ++d) {
    double km = (double)kmat[(size_t)t * ND + d];
    a0 += km * vb[(size_t)b * ND + d];
    a1 += km * u[d];
  }
  c0[t] = (float)a0;
  c1[t] = (float)a1;
}

// KM[t][j] = sum_d kmat[t][d]*M[d][j]
__global__ __launch_bounds__(128) void k_KM(const float* __restrict__ kmat, const double* __restrict__ M,
                                            float* __restrict__ KM) {
  int t = blockIdx.x, j = threadIdx.x;
  __shared__ float kms[ND];
  kms[j] = kmat[(size_t)t * ND + j];
  __syncthreads();
  double acc = 0.0;
  for (int d = 0; d < ND; ++d) acc += (double)kms[d] * M[(size_t)d * ND + j];
  KM[(size_t)t * ND + j] = (float)acc;
}

// P[b][c][n] = sum_j KM[b*NN+n][j] * h[b*NN+c][j]  (block = b*NN+c)
__global__ __launch_bounds__(256) void k_P(const float* __restrict__ KM, const float* __restrict__ h,
                                           float* __restrict__ P) {
  int blk = blockIdx.x, tid = threadIdx.x;
  int b = blk / NN;
  __shared__ float hrow[ND];
  if (tid < ND) hrow[tid] = h[(size_t)blk * ND + tid];
  __syncthreads();
  if (tid < NN) {
    const float* kr = KM + (size_t)(b * NN + tid) * ND;
    double acc = 0.0;
    for (int j = 0; j < ND; ++j) acc += (double)kr[j] * (double)hrow[j];
    P[(size_t)blk * NN + tid] = (float)acc;
  }
}

// ---------------- decode: one block per batch row; OUTPUT IS FLOAT32 ----------------
__global__ __launch_bounds__(256) void k_decode(const float* __restrict__ P, const float* __restrict__ c0,
                                                const float* __restrict__ c1, const float* __restrict__ dr,
                                                const unsigned* __restrict__ rng, float* __restrict__ out) {
  const int b = blockIdx.x, tid = threadIdx.x;
  const int lane = tid & 63, w = tid >> 6;
  __shared__ float drs[NN], c0s[NN], c1s[NN], smask[256];
  __shared__ unsigned char vis[NN];
  __shared__ float pv[4], pm[4];
  __shared__ int pi[4];
  __shared__ double ps[4];
  __shared__ int s_cur, s_done, s_anyf, s_anyns;
  __shared__ float s_rem, s_m;
  if (tid < NN) {
    drs[tid] = dr[b * NN + tid];
    c0s[tid] = c0[b * NN + tid];
    c1s[tid] = c1[b * NN + tid];
    vis[tid] = 0;
  }
  if (tid == 0) {
    s_cur = 0; s_done = 0; s_rem = 1.0f; s_anyf = 0; s_anyns = 0;
    out[(size_t)b * 400] = 0.0f;
  }
  float lpsum = 0.0f;
  __syncthreads();
  const float SQD = 11.3137084989847603f;  // f32(sqrt(128))
  for (int t = 0; t < NSTEP; ++t) {
    const int cur = s_cur, done = s_done;
    const float rem = s_rem;
    const unsigned sk0 = rng[2 * t], sk1 = rng[2 * t + 1];
    bool visn = (tid < NN) ? (vis[tid] != 0) : true;
    float drn = (tid < NN) ? drs[tid] : 1e9f;
    if (tid >= 1 && tid < NN && !visn && drn <= rem) s_anyf = 1;
    if (tid >= 1 && tid < NN && !visn) s_anyns = 1;
    __syncthreads();
    const int has_feas = s_anyf, all_served = !s_anyns;
    const bool at_depot = (cur == 0) && !done, not_depot = (cur != 0) && !done;
    const bool depot_mask = (at_depot && has_feas) || (not_depot && has_feas && !all_served);
    float masked, score;
    if (tid < NN) {
      float Pv = P[((size_t)(b * NN + cur)) * NN + tid];
      double sd = (double)Pv + (double)c0s[tid] + (double)rem * (double)c1s[tid];
      float logit = (float)sd / SQD;
      bool infn = visn || (drn > rem) || (tid == 0 && depot_mask);
      masked = infn ? -1e9f : logit;
#if RNG_PARTITIONABLE
      unsigned o0, o1;
      tf2x32(sk0, sk1, 0u, (unsigned)(b * NN + tid), &o0, &o1);
      unsigned bits = o0 ^ o1;  // jax partitionable 32-bit stream: bits1 ^ bits2
#else
      unsigned o0, o1, bits;
      unsigned j = (unsigned)(b * NN + tid);
      if (j < 12800u) { tf2x32(sk0, sk1, j, j + 12800u, &o0, &o1); bits = o0; }
      else { tf2x32(sk0, sk1, j - 12800u, j, &o0, &o1); bits = o1; }
#endif
      float u01 = __uint_as_float((bits >> 9) | 0x3f800000u) - 1.0f;
      float uu = fmaxf(1.17549435082228751e-38f, u01);
      float g = (float)(-log(-log((double)uu)));
      score = masked + g;
    } else {
      masked = -3.0e38f;
      score = -3.0e38f;
    }
    smask[tid] = masked;
    float v = score, mm = masked;
    int vi = tid;
    for (int off = 32; off; off >>= 1) {
      float ov = __shfl_down(v, off, 64);
      int oi = __shfl_down(vi, off, 64);
      float om = __shfl_down(mm, off, 64);
      if (ov > v || (ov == v && oi < vi)) { v = ov; vi = oi; }
      mm = fmaxf(mm, om);
    }
    if (lane == 0) { pv[w] = v; pi[w] = vi; pm[w] = mm; }
    __syncthreads();
    if (tid == 0) {
      float bv = pv[0], bm = pm[0];
      int bi = pi[0];
      for (int w2 = 1; w2 < 4; ++w2) {
        if (pv[w2] > bv || (pv[w2] == bv && pi[w2] < bi)) { bv = pv[w2]; bi = pi[w2]; }
        bm = fmaxf(bm, pm[w2]);
      }
      s_m = bm;
      pi[0] = bi;
      s_anyf = 0; s_anyns = 0;
    }
    __syncthreads();
    const float m = s_m;
    double e = (tid < NN) ? exp((double)(smask[tid] - m)) : 0.0;
    double ev = e;
    for (int off = 32; off; off >>= 1) ev += __shfl_down(ev, off, 64);
    if (lane == 0) ps[w] = ev;
    __syncthreads();
    if (tid == 0) {
      double stot = ps[0] + ps[1] + ps[2] + ps[3];
      int sel = pi[0];
      float slp = (smask[sel] - m) - (float)log(stot);
      bool force = (all_served && cur != 0 && !done) || (not_depot && !has_feas) || done;
      if (force) { sel = 0; slp = 0.0f; }
      out[(size_t)b * 400 + 1 + t] = (float)sel;
      lpsum += slp;
      bool isd = (sel == 0);
      float nr = isd ? 1.0f : (rem - drs[sel]);
      nr = fminf(fmaxf(nr, 0.0f), 1.0f);
      s_rem = nr;
      if (!isd) vis[sel] = 1;
      if (all_served && sel == 0) s_done = 1;
      s_cur = sel;
    }
    __syncthreads();
  }
  if (tid == 0) out[(size_t)NB * 400 + b] = lpsum;
}

// ---------------- host ----------------
extern "C" void kernel_launch(void* const* d_in, const int* in_sizes, int n_in,
                              void* d_out, int out_size, void* d_ws, size_t ws_size,
                              hipStream_t stream) {
  (void)in_sizes; (void)n_in; (void)out_size; (void)ws_size;
  const float* coords = (const float*)d_in[0];
  const float* dem    = (const float*)d_in[1];
  const float* cap    = (const float*)d_in[2];
  const float* eW     = (const float*)d_in[3];
  const float* eb     = (const float*)d_in[4];
  const float* Wqkv   = (const float*)d_in[5];
  const float* bqkv   = (const float*)d_in[6];
  const float* Wo     = (const float*)d_in[7];
  const float* bo     = (const float*)d_in[8];
  const float* W1     = (const float*)d_in[9];
  const float* b1     = (const float*)d_in[10];
  const float* W2     = (const float*)d_in[11];
  const float* b2     = (const float*)d_in[12];
  const float* ln1g   = (const float*)d_in[13];
  const float* ln1b   = (const float*)d_in[14];
  const float* ln2g   = (const float*)d_in[15];
  const float* ln2b   = (const float*)d_in[16];
  const float* Wq     = (const float*)d_in[17];
  const float* Wk     = (const float*)d_in[18];
  const float* Wcap   = (const float*)d_in[19];
  const float* bcap   = (const float*)d_in[20];
  const float* Wctx   = (const float*)d_in[21];
  const float* bctx   = (const float*)d_in[22];

  char* ws = (char*)d_ws;
  size_t off = 0;
  auto take = [&](size_t bytes) -> void* {
    void* p = ws + off;
    off += (bytes + 255) & ~(size_t)255;
    return p;
  };
  float* h    = (float*)take((size_t)NT * ND * 4);
  float* dr   = (float*)take((size_t)NT * 4);
  float* qkv  = (float*)take((size_t)NT * 384 * 4);
  float* att  = (float*)take((size_t)NT * ND * 4);
  float* kmat = (float*)take((size_t)NT * ND * 4);
  float* P    = (float*)take((size_t)NB * NN * NN * 4);
  float* c0   = (float*)take((size_t)NT * 4);
  float* c1   = (float*)take((size_t)NT * 4);
  float* gctx = (float*)take((size_t)NB * ND * 4);
  double* M   = (double*)take((size_t)ND * ND * 8);
  double* u   = (double*)take((size_t)ND * 8);
  double* t1  = (double*)take((size_t)ND * 8);
  double* wu  = (double*)take((size_t)ND * 8);
  double* t2  = (double*)take((size_t)NB * ND * 8);
  double* vb  = (double*)take((size_t)NB * ND * 8);
  unsigned* rng = (unsigned*)take((size_t)NSTEP * 2 * 4);
  float* KM = qkv;  // reuse (qkv dead after attention+oln)

  k_rng<<<1, 1, 0, stream>>>(rng);
  k_embed<<<(NT * ND) / 256, 256, 0, stream>>>(coords, dem, cap, eW, eb, h, dr);
  for (int i = 0; i < NL; ++i) {
    k_qkv<<<NT, 384, 0, stream>>>(h, Wqkv + (size_t)i * 384 * ND, bqkv + (size_t)i * 384, qkv);
    k_attn<<<NB * NH, 256, 0, stream>>>(qkv, att);
    k_oln<<<NT, 128, 0, stream>>>(att, Wo + (size_t)i * ND * ND, bo + (size_t)i * ND,
                                  ln1g + (size_t)i * ND, ln1b + (size_t)i * ND, h);
    k_ffn<<<NT / FT, 256, 0, stream>>>(h, W1 + (size_t)i * NF * ND, b1 + (size_t)i * NF,
                                       W2 + (size_t)i * ND * NF, b2 + (size_t)i * ND,
                                       ln2g + (size_t)i * ND, ln2b + (size_t)i * ND);
  }
  k_gctx<<<NB, 128, 0, stream>>>(h, gctx);
  k_kmat<<<NT, 128, 0, stream>>>(h, Wk, kmat);
  k_prep1<<<1, 128, 0, stream>>>(Wctx, bcap, Wcap, bctx, t1, wu);
  k_M<<<ND, 128, 0, stream>>>(Wq, Wctx, M);
  k_u<<<1, 128, 0, stream>>>(Wq, wu, u);
  k_t2<<<NB, 128, 0, stream>>>(Wctx, gctx, t2);
  k_vb<<<NB, 128, 0, stream>>>(Wq, t2, t1, vb);
  k_c01<<<NT / 256, 256, 0, stream>>>(kmat, vb, u, c0, c1);
  k_KM<<<NT, 128, 0, stream>>>(kmat, M, KM);
  k_P<<<NT, 256, 0, stream>>>(KM, h, P);
  k_decode<<<NB, 256, 0, stream>>>(P, c0, c1, dr, rng, (float*)d_out);
}

// Round 5
// 6568.539 us; speedup vs baseline: 1.6525x; 1.6525x over previous
//
#include <hip/hip_runtime.h>
#include <hip/hip_bf16.h>
#include <stdint.h>
#include <math.h>

#define NB 128
#define NN 200
#define ND 128
#define NH 8
#define DH 16
#define NL 3
#define NF 2048
#define NT (NB * NN)
#define NSTEP 399
#define RNG_PARTITIONABLE 1

// ---------------- Threefry-2x32 (JAX-compatible) ----------------
__host__ __device__ inline void tf2x32(unsigned k0, unsigned k1, unsigned x0, unsigned x1,
                                       unsigned* o0, unsigned* o1) {
  unsigned ks[3] = {k0, k1, k0 ^ k1 ^ 0x1BD11BDAu};
  x0 += ks[0]; x1 += ks[1];
  const unsigned R[2][4] = {{13u, 15u, 26u, 6u}, {17u, 29u, 16u, 24u}};
#pragma unroll
  for (int i = 0; i < 5; ++i) {
#pragma unroll
    for (int j = 0; j < 4; ++j) {
      unsigned r = R[i & 1][j];
      x0 += x1;
      x1 = (x1 << r) | (x1 >> (32u - r));
      x1 ^= x0;
    }
    x0 += ks[(i + 1) % 3];
    x1 += ks[(i + 2) % 3] + (unsigned)(i + 1);
  }
  *o0 = x0; *o1 = x1;
}

__global__ void k_rng(unsigned* __restrict__ rng) {
  unsigned k0 = 0u, k1 = 42u;
  for (int t = 0; t < NSTEP; ++t) {
#if RNG_PARTITIONABLE
    unsigned a0, a1, s0, s1;
    tf2x32(k0, k1, 0u, 1u, &s0, &s1);
    tf2x32(k0, k1, 0u, 0u, &a0, &a1);
    rng[2 * t] = s0; rng[2 * t + 1] = s1;
    k0 = a0; k1 = a1;
#else
    unsigned a0, a1, b0_, b1_;
    tf2x32(k0, k1, 0u, 2u, &a0, &a1);
    tf2x32(k0, k1, 1u, 3u, &b0_, &b1_);
    rng[2 * t] = a1; rng[2 * t + 1] = b1_;
    k0 = a0; k1 = b0_;
#endif
  }
}

// ---------------- transpose: dst[c][r] = src[r][c]; dst linear-coalesced ----------------
__global__ void k_tr(const float* __restrict__ src, float* __restrict__ dst, int R, int C) {
  int i = blockIdx.x * 256 + threadIdx.x;
  if (i >= R * C) return;
  int c = i / R, r = i - c * R;
  dst[i] = src[(size_t)r * C + c];
}

// ---------------- embed ----------------
__global__ void k_embed(const float* __restrict__ coords, const float* __restrict__ dem,
                        const float* __restrict__ cap, const float* __restrict__ eW,
                        const float* __restrict__ eb, float* __restrict__ h, float* __restrict__ dr) {
  int gid = blockIdx.x * blockDim.x + threadIdx.x;
  int t = gid >> 7, d = gid & 127;
  int b = t / NN;
  float drv = dem[t] / cap[b];
  double acc = (double)eW[d * 3] * (double)coords[2 * t]
             + (double)eW[d * 3 + 1] * (double)coords[2 * t + 1]
             + (double)eW[d * 3 + 2] * (double)drv;
  h[gid] = (float)acc + eb[d];
  if (d == 0) dr[t] = drv;
}

// ---------------- qkv: 8 tokens/block, thread j owns 8 acc chains ----------------
#define QT 8
__global__ __launch_bounds__(384) void k_qkv(const float* __restrict__ h, const float* __restrict__ WT,
                                             const float* __restrict__ bias, float* __restrict__ qkv) {
  const int t0 = blockIdx.x * QT, j = threadIdx.x;
  __shared__ double hsh[ND][QT];
  for (int idx = j; idx < ND * QT; idx += 384) {
    int t = idx & 7, k = idx >> 3;
    hsh[k][t] = (double)h[(size_t)(t0 + t) * ND + k];
  }
  __syncthreads();
  double acc[QT];
#pragma unroll
  for (int t = 0; t < QT; ++t) acc[t] = 0.0;
  for (int k = 0; k < ND; ++k) {
    double w = (double)WT[(size_t)k * 384 + j];
#pragma unroll
    for (int t = 0; t < QT; ++t) acc[t] += w * hsh[k][t];
  }
  float bv = bias[j];
#pragma unroll
  for (int t = 0; t < QT; ++t)
    qkv[(size_t)(t0 + t) * 384 + j] = (float)acc[t] + bv;
}

// ---------------- attention (unchanged, known-correct) ----------------
__global__ __launch_bounds__(256) void k_attn(const float* __restrict__ qkv, float* __restrict__ att) {
  const int b = blockIdx.x / NH, hh = blockIdx.x % NH, tid = threadIdx.x;
  const int lane = tid & 63, w = tid >> 6;
  __shared__ float ksh[NN][DH + 1];
  __shared__ float vsh[NN][DH + 1];
  __shared__ float ash[NN];
  __shared__ float qsh[DH];
  __shared__ float redf[4];
  __shared__ double redd[4];
  __shared__ double pp[16][DH + 1];
  __shared__ float s_m;
  __shared__ double s_sum;
  for (int idx = tid; idx < NN * DH; idx += 256) {
    int n = idx / DH, d2 = idx % DH;
    size_t base = (size_t)(b * NN + n) * 384 + hh * DH + d2;
    ksh[n][d2] = qkv[base + ND];
    vsh[n][d2] = qkv[base + 2 * ND];
  }
  __syncthreads();
  for (int qn = 0; qn < NN; ++qn) {
    if (tid < DH) qsh[tid] = qkv[(size_t)(b * NN + qn) * 384 + hh * DH + tid];
    __syncthreads();
    float s = -3.0e38f;
    if (tid < NN) {
      double acc = 0.0;
#pragma unroll
      for (int d2 = 0; d2 < DH; ++d2) acc += (double)qsh[d2] * (double)ksh[tid][d2];
      s = (float)acc / 4.0f;
    }
    float mv = s;
    for (int off = 32; off; off >>= 1) mv = fmaxf(mv, __shfl_down(mv, off, 64));
    if (lane == 0) redf[w] = mv;
    __syncthreads();
    if (tid == 0) s_m = fmaxf(fmaxf(redf[0], redf[1]), fmaxf(redf[2], redf[3]));
    __syncthreads();
    float m = s_m;
    double e = 0.0;
    if (tid < NN) e = exp((double)(s - m));
    double ev = e;
    for (int off = 32; off; off >>= 1) ev += __shfl_down(ev, off, 64);
    if (lane == 0) redd[w] = ev;
    __syncthreads();
    if (tid == 0) s_sum = redd[0] + redd[1] + redd[2] + redd[3];
    __syncthreads();
    if (tid < NN) ash[tid] = (float)(e / s_sum);
    __syncthreads();
    {
      int c = tid >> 4, d2 = tid & 15;
      double acc = 0.0;
      for (int n = c; n < NN; n += 16) acc += (double)ash[n] * (double)vsh[n][d2];
      pp[c][d2] = acc;
    }
    __syncthreads();
    if (tid < DH) {
      double o = 0.0;
#pragma unroll
      for (int c = 0; c < 16; ++c) o += pp[c][tid];
      att[(size_t)(b * NN + qn) * ND + hh * DH + tid] = (float)o;
    }
    __syncthreads();
  }
}

// ---------------- o-proj + residual + LN1: 4 tokens/block, register-tiled ----------------
#define OT 4
__global__ __launch_bounds__(128) void k_oln(const float* __restrict__ att, const float* __restrict__ WoT,
                                             const float* __restrict__ bo, const float* __restrict__ g,
                                             const float* __restrict__ bb, float* __restrict__ h) {
  const int t0 = blockIdx.x * OT, d = threadIdx.x;
  __shared__ double ash[ND][OT];
  __shared__ float xsh[OT][ND];
  __shared__ float mred[OT], sred[OT];
  for (int idx = d; idx < ND * OT; idx += 128) {
    int t = idx & 3, k = idx >> 2;
    ash[k][t] = (double)att[(size_t)(t0 + t) * ND + k];
  }
  __syncthreads();
  double acc[OT];
#pragma unroll
  for (int t = 0; t < OT; ++t) acc[t] = 0.0;
  for (int k = 0; k < ND; ++k) {
    double w = (double)WoT[(size_t)k * ND + d];
#pragma unroll
    for (int t = 0; t < OT; ++t) acc[t] += w * ash[k][t];
  }
  float bv = bo[d];
#pragma unroll
  for (int t = 0; t < OT; ++t) {
    float o = (float)acc[t] + bv;
    xsh[t][d] = h[(size_t)(t0 + t) * ND + d] + o;
  }
  __syncthreads();
  if (d < OT) {
    double sv = 0.0;
    for (int k = 0; k < ND; ++k) sv += (double)xsh[d][k];
    float m = (float)(sv / 128.0);
    double sq = 0.0;
    for (int k = 0; k < ND; ++k) { float tf = xsh[d][k] - m; sq += (double)tf * (double)tf; }
    mred[d] = m;
    sred[d] = sqrtf((float)(sq / 128.0) + 1e-5f);
  }
  __syncthreads();
#pragma unroll
  for (int t = 0; t < OT; ++t) {
    float tf = xsh[t][d] - mred[t];
    h[(size_t)(t0 + t) * ND + d] = tf / sred[t] * g[d] + bb[d];
  }
}

// ---------------- FFN + residual + LN2: 4 tokens/block, register-tiled ----------------
#define FT 4
__global__ __launch_bounds__(256) void k_ffn(float* __restrict__ h, const float* __restrict__ W1T,
                                             const float* __restrict__ b1, const float* __restrict__ W2T,
                                             const float* __restrict__ b2, const float* __restrict__ g,
                                             const float* __restrict__ bb) {
  const int t0 = blockIdx.x * FT, tid = threadIdx.x;
  __shared__ double hsh[ND][FT];   // 4 KB
  __shared__ double fsh[NF][FT];   // 64 KB (also reused as reduction buffer)
  __shared__ float xsh[FT][ND];    // 2 KB
  __shared__ float mred[FT], sred[FT];
  for (int idx = tid; idx < ND * FT; idx += 256) {
    int t = idx & 3, k = idx >> 2;
    hsh[k][t] = (double)h[(size_t)(t0 + t) * ND + k];
  }
  __syncthreads();
  // ---- phase 1: f = relu(h @ W1^T + b1), thread -> 8 consecutive j x 4 tokens ----
  {
    const int j0 = tid * 8;
    double acc[8][FT];
#pragma unroll
    for (int a = 0; a < 8; ++a)
#pragma unroll
      for (int t = 0; t < FT; ++t) acc[a][t] = 0.0;
    for (int k = 0; k < ND; ++k) {
      double h0 = hsh[k][0], h1 = hsh[k][1], h2 = hsh[k][2], h3 = hsh[k][3];
      const float* wp = W1T + (size_t)k * NF + j0;
      float4 wa = *(const float4*)wp;
      float4 wb = *(const float4*)(wp + 4);
      double wv[8] = {(double)wa.x, (double)wa.y, (double)wa.z, (double)wa.w,
                      (double)wb.x, (double)wb.y, (double)wb.z, (double)wb.w};
#pragma unroll
      for (int a = 0; a < 8; ++a) {
        acc[a][0] += wv[a] * h0;
        acc[a][1] += wv[a] * h1;
        acc[a][2] += wv[a] * h2;
        acc[a][3] += wv[a] * h3;
      }
    }
#pragma unroll
    for (int a = 0; a < 8; ++a) {
      float bv = b1[j0 + a];
#pragma unroll
      for (int t = 0; t < FT; ++t) {
        float f = (float)acc[a][t] + bv;             // f32 round at tensor boundary
        fsh[j0 + a][t] = (double)fmaxf(f, 0.0f);
      }
    }
  }
  __syncthreads();
  // ---- phase 2: o = f @ W2^T + b2; 4 wave-groups split the j range ----
  double acc2[2][FT];
  const int d0 = (tid & 63) * 2, grp = tid >> 6;
  {
    const int jbeg = grp * (NF / 4), jend = jbeg + NF / 4;
#pragma unroll
    for (int a = 0; a < 2; ++a)
#pragma unroll
      for (int t = 0; t < FT; ++t) acc2[a][t] = 0.0;
    for (int j = jbeg; j < jend; ++j) {
      double f0 = fsh[j][0], f1 = fsh[j][1], f2 = fsh[j][2], f3 = fsh[j][3];
      const float* wp = W2T + (size_t)j * ND + d0;
      float2 wv = *(const float2*)wp;
      double w0 = (double)wv.x, w1 = (double)wv.y;
      acc2[0][0] += w0 * f0; acc2[0][1] += w0 * f1; acc2[0][2] += w0 * f2; acc2[0][3] += w0 * f3;
      acc2[1][0] += w1 * f0; acc2[1][1] += w1 * f1; acc2[1][2] += w1 * f2; acc2[1][3] += w1 * f3;
    }
  }
  __syncthreads();
  double* red = &fsh[0][0];  // 2048 doubles: red[(d*FT+t)*4 + grp]
  {
#pragma unroll
    for (int a = 0; a < 2; ++a)
#pragma unroll
      for (int t = 0; t < FT; ++t)
        red[((d0 + a) * FT + t) * 4 + grp] = acc2[a][t];
  }
  __syncthreads();
  for (int idx = tid; idx < ND * FT; idx += 256) {
    int d = idx >> 2, t = idx & 3;
    const double* rp = red + (size_t)(d * FT + t) * 4;
    double s = rp[0] + rp[1] + rp[2] + rp[3];
    float o = (float)s + b2[d];
    float hf = (float)hsh[d][t];
    xsh[t][d] = hf + o;
  }
  __syncthreads();
  if (tid < FT) {
    double sv = 0.0;
    for (int d = 0; d < ND; ++d) sv += (double)xsh[tid][d];
    float m = (float)(sv / 128.0);
    double sq = 0.0;
    for (int d = 0; d < ND; ++d) { float tf = xsh[tid][d] - m; sq += (double)tf * (double)tf; }
    mred[tid] = m;
    sred[tid] = sqrtf((float)(sq / 128.0) + 1e-5f);
  }
  __syncthreads();
  for (int idx = tid; idx < ND * FT; idx += 256) {
    int d = idx & 127, t = idx >> 7;
    float tf = xsh[t][d] - mred[t];
    h[(size_t)(t0 + t) * ND + d] = tf / sred[t] * g[d] + bb[d];
  }
}

// ---------------- decode precompute (unchanged) ----------------
__global__ __launch_bounds__(128) void k_gctx(const float* __restrict__ h, float* __restrict__ gctx) {
  int b = blockIdx.x, d = threadIdx.x;
  double acc = 0.0;
  for (int n = 0; n < NN; ++n) acc += (double)h[(size_t)(b * NN + n) * ND + d];
  gctx[b * ND + d] = (float)(acc / 200.0);
}

__global__ __launch_bounds__(128) void k_kmat(const float* __restrict__ h, const float* __restrict__ Wk,
                                              float* __restrict__ kmat) {
  int t = blockIdx.x, d = threadIdx.x;
  __shared__ float hrow[ND];
  hrow[d] = h[(size_t)t * ND + d];
  __syncthreads();
  double acc = 0.0;
  const float* wr = Wk + (size_t)d * ND;
  for (int k = 0; k < ND; ++k) acc += (double)hrow[k] * (double)wr[k];
  kmat[(size_t)t * ND + d] = (float)acc;
}

__global__ __launch_bounds__(128) void k_prep1(const float* __restrict__ Wctx, const float* __restrict__ bcap,
                                               const float* __restrict__ Wcap, const float* __restrict__ bctx,
                                               double* __restrict__ t1, double* __restrict__ wu) {
  int k = threadIdx.x;
  double a = 0.0, c = 0.0;
  for (int m = 0; m < ND; ++m) {
    double wc = (double)Wctx[(size_t)k * 384 + 256 + m];
    a += wc * (double)bcap[m];
    c += wc * (double)Wcap[m];
  }
  t1[k] = a + (double)bctx[k];
  wu[k] = c;
}

__global__ __launch_bounds__(128) void k_M(const float* __restrict__ Wq, const float* __restrict__ Wctx,
                                           double* __restrict__ M) {
  int d = blockIdx.x, j = threadIdx.x;
  double acc = 0.0;
  for (int k = 0; k < ND; ++k)
    acc += (double)Wq[(size_t)d * ND + k] * (double)Wctx[(size_t)k * 384 + j];
  M[(size_t)d * ND + j] = acc;
}

__global__ __launch_bounds__(128) void k_u(const float* __restrict__ Wq, const double* __restrict__ wu,
                                           double* __restrict__ u) {
  int d = threadIdx.x;
  double acc = 0.0;
  for (int k = 0; k < ND; ++k) acc += (double)Wq[(size_t)d * ND + k] * wu[k];
  u[d] = acc;
}

__global__ __launch_bounds__(128) void k_t2(const float* __restrict__ Wctx, const float* __restrict__ gctx,
                                            double* __restrict__ t2) {
  int b = blockIdx.x, k = threadIdx.x;
  double acc = 0.0;
  for (int m = 0; m < ND; ++m)
    acc += (double)Wctx[(size_t)k * 384 + 128 + m] * (double)gctx[b * ND + m];
  t2[(size_t)b * ND + k] = acc;
}

__global__ __launch_bounds__(128) void k_vb(const float* __restrict__ Wq, const double* __restrict__ t2,
                                            const double* __restrict__ t1, double* __restrict__ vb) {
  int b = blockIdx.x, d = threadIdx.x;
  double acc = 0.0;
  for (int k = 0; k < ND; ++k)
    acc += (double)Wq[(size_t)d * ND + k] * (t2[(size_t)b * ND + k] + t1[k]);
  vb[(size_t)b * ND + d] = acc;
}

__global__ __launch_bounds__(256) void k_c01(const float* __restrict__ kmat, const double* __restrict__ vb,
                                             const double* __restrict__ u, float* __restrict__ c0, float* __restrict__ c1) {
  int t = blockIdx.x * 256 + threadIdx.x;
  if (t >= NT) return;
  int b = t / NN;
  double a0 = 0.0, a1 = 0.0;
  for (int d = 0; d < ND; ++d) {
    double km = (double)kmat[(size_t)t * ND + d];
    a0 += km * vb[(size_t)b * ND + d];
    a1 += km * u[d];
  }
  c0[t] = (float)a0;
  c1[t] = (float)a1;
}

__global__ __launch_bounds__(128) void k_KM(const float* __restrict__ kmat, const double* __restrict__ M,
                                            float* __restrict__ KM) {
  int t = blockIdx.x, j = threadIdx.x;
  __shared__ float kms[ND];
  kms[j] = kmat[(size_t)t * ND + j];
  __syncthreads();
  double acc = 0.0;
  for (int d = 0; d < ND; ++d) acc += (double)kms[d] * M[(size_t)d * ND + j];
  KM[(size_t)t * ND + j] = (float)acc;
}

__global__ __launch_bounds__(256) void k_P(const float* __restrict__ KM, const float* __restrict__ h,
                                           float* __restrict__ P) {
  int blk = blockIdx.x, tid = threadIdx.x;
  int b = blk / NN;
  __shared__ float hrow[ND];
  if (tid < ND) hrow[tid] = h[(size_t)blk * ND + tid];
  __syncthreads();
  if (tid < NN) {
    const float* kr = KM + (size_t)(b * NN + tid) * ND;
    double acc = 0.0;
    for (int j = 0; j < ND; ++j) acc += (double)kr[j] * (double)hrow[j];
    P[(size_t)blk * NN + tid] = (float)acc;
  }
}

// ---------------- decode (unchanged, f32 output) ----------------
__global__ __launch_bounds__(256) void k_decode(const float* __restrict__ P, const float* __restrict__ c0,
                                                const float* __restrict__ c1, const float* __restrict__ dr,
                                                const unsigned* __restrict__ rng, float* __restrict__ out) {
  const int b = blockIdx.x, tid = threadIdx.x;
  const int lane = tid & 63, w = tid >> 6;
  __shared__ float drs[NN], c0s[NN], c1s[NN], smask[256];
  __shared__ unsigned char vis[NN];
  __shared__ float pv[4], pm[4];
  __shared__ int pi[4];
  __shared__ double ps[4];
  __shared__ int s_cur, s_done, s_anyf, s_anyns;
  __shared__ float s_rem, s_m;
  if (tid < NN) {
    drs[tid] = dr[b * NN + tid];
    c0s[tid] = c0[b * NN + tid];
    c1s[tid] = c1[b * NN + tid];
    vis[tid] = 0;
  }
  if (tid == 0) {
    s_cur = 0; s_done = 0; s_rem = 1.0f; s_anyf = 0; s_anyns = 0;
    out[(size_t)b * 400] = 0.0f;
  }
  float lpsum = 0.0f;
  __syncthreads();
  const float SQD = 11.3137084989847603f;
  for (int t = 0; t < NSTEP; ++t) {
    const int cur = s_cur, done = s_done;
    const float rem = s_rem;
    const unsigned sk0 = rng[2 * t], sk1 = rng[2 * t + 1];
    bool visn = (tid < NN) ? (vis[tid] != 0) : true;
    float drn = (tid < NN) ? drs[tid] : 1e9f;
    if (tid >= 1 && tid < NN && !visn && drn <= rem) s_anyf = 1;
    if (tid >= 1 && tid < NN && !visn) s_anyns = 1;
    __syncthreads();
    const int has_feas = s_anyf, all_served = !s_anyns;
    const bool at_depot = (cur == 0) && !done, not_depot = (cur != 0) && !done;
    const bool depot_mask = (at_depot && has_feas) || (not_depot && has_feas && !all_served);
    float masked, score;
    if (tid < NN) {
      float Pv = P[((size_t)(b * NN + cur)) * NN + tid];
      double sd = (double)Pv + (double)c0s[tid] + (double)rem * (double)c1s[tid];
      float logit = (float)sd / SQD;
      bool infn = visn || (drn > rem) || (tid == 0 && depot_mask);
      masked = infn ? -1e9f : logit;
#if RNG_PARTITIONABLE
      unsigned o0, o1;
      tf2x32(sk0, sk1, 0u, (unsigned)(b * NN + tid), &o0, &o1);
      unsigned bits = o0 ^ o1;
#else
      unsigned o0, o1, bits;
      unsigned j = (unsigned)(b * NN + tid);
      if (j < 12800u) { tf2x32(sk0, sk1, j, j + 12800u, &o0, &o1); bits = o0; }
      else { tf2x32(sk0, sk1, j - 12800u, j, &o0, &o1); bits = o1; }
#endif
      float u01 = __uint_as_float((bits >> 9) | 0x3f800000u) - 1.0f;
      float uu = fmaxf(1.17549435082228751e-38f, u01);
      float g = (float)(-log(-log((double)uu)));
      score = masked + g;
    } else {
      masked = -3.0e38f;
      score = -3.0e38f;
    }
    smask[tid] = masked;
    float v = score, mm = masked;
    int vi = tid;
    for (int off = 32; off; off >>= 1) {
      float ov = __shfl_down(v, off, 64);
      int oi = __shfl_down(vi, off, 64);
      float om = __shfl_down(mm, off, 64);
      if (ov > v || (ov == v && oi < vi)) { v = ov; vi = oi; }
      mm = fmaxf(mm, om);
    }
    if (lane == 0) { pv[w] = v; pi[w] = vi; pm[w] = mm; }
    __syncthreads();
    if (tid == 0) {
      float bv = pv[0], bm = pm[0];
      int bi = pi[0];
      for (int w2 = 1; w2 < 4; ++w2) {
        if (pv[w2] > bv || (pv[w2] == bv && pi[w2] < bi)) { bv = pv[w2]; bi = pi[w2]; }
        bm = fmaxf(bm, pm[w2]);
      }
      s_m = bm;
      pi[0] = bi;
      s_anyf = 0; s_anyns = 0;
    }
    __syncthreads();
    const float m = s_m;
    double e = (tid < NN) ? exp((double)(smask[tid] - m)) : 0.0;
    double ev = e;
    for (int off = 32; off; off >>= 1) ev += __shfl_down(ev, off, 64);
    if (lane == 0) ps[w] = ev;
    __syncthreads();
    if (tid == 0) {
      double stot = ps[0] + ps[1] + ps[2] + ps[3];
      int sel = pi[0];
      float slp = (smask[sel] - m) - (float)log(stot);
      bool force = (all_served && cur != 0 && !done) || (not_depot && !has_feas) || done;
      if (force) { sel = 0; slp = 0.0f; }
      out[(size_t)b * 400 + 1 + t] = (float)sel;
      lpsum += slp;
      bool isd = (sel == 0);
      float nr = isd ? 1.0f : (rem - drs[sel]);
      nr = fminf(fmaxf(nr, 0.0f), 1.0f);
      s_rem = nr;
      if (!isd) vis[sel] = 1;
      if (all_served && sel == 0) s_done = 1;
      s_cur = sel;
    }
    __syncthreads();
  }
  if (tid == 0) out[(size_t)NB * 400 + b] = lpsum;
}

// ---------------- host ----------------
extern "C" void kernel_launch(void* const* d_in, const int* in_sizes, int n_in,
                              void* d_out, int out_size, void* d_ws, size_t ws_size,
                              hipStream_t stream) {
  (void)in_sizes; (void)n_in; (void)out_size; (void)ws_size;
  const float* coords = (const float*)d_in[0];
  const float* dem    = (const float*)d_in[1];
  const float* cap    = (const float*)d_in[2];
  const float* eW     = (const float*)d_in[3];
  const float* eb     = (const float*)d_in[4];
  const float* Wqkv   = (const float*)d_in[5];
  const float* bqkv   = (const float*)d_in[6];
  const float* Wo     = (const float*)d_in[7];
  const float* bo     = (const float*)d_in[8];
  const float* W1     = (const float*)d_in[9];
  const float* b1     = (const float*)d_in[10];
  const float* W2     = (const float*)d_in[11];
  const float* b2     = (const float*)d_in[12];
  const float* ln1g   = (const float*)d_in[13];
  const float* ln1b   = (const float*)d_in[14];
  const float* ln2g   = (const float*)d_in[15];
  const float* ln2b   = (const float*)d_in[16];
  const float* Wq     = (const float*)d_in[17];
  const float* Wk     = (const float*)d_in[18];
  const float* Wcap   = (const float*)d_in[19];
  const float* bcap   = (const float*)d_in[20];
  const float* Wctx   = (const float*)d_in[21];
  const float* bctx   = (const float*)d_in[22];

  char* ws = (char*)d_ws;
  size_t off = 0;
  auto take = [&](size_t bytes) -> void* {
    void* p = ws + off;
    off += (bytes + 255) & ~(size_t)255;
    return p;
  };
  float* h    = (float*)take((size_t)NT * ND * 4);
  float* dr   = (float*)take((size_t)NT * 4);
  float* qkv  = (float*)take((size_t)NT * 384 * 4);
  float* att  = (float*)take((size_t)NT * ND * 4);
  float* kmat = (float*)take((size_t)NT * ND * 4);
  float* P    = (float*)take((size_t)NB * NN * NN * 4);
  float* c0   = (float*)take((size_t)NT * 4);
  float* c1   = (float*)take((size_t)NT * 4);
  float* gctx = (float*)take((size_t)NB * ND * 4);
  double* M   = (double*)take((size_t)ND * ND * 8);
  double* u   = (double*)take((size_t)ND * 8);
  double* t1  = (double*)take((size_t)ND * 8);
  double* wu  = (double*)take((size_t)ND * 8);
  double* t2  = (double*)take((size_t)NB * ND * 8);
  double* vb  = (double*)take((size_t)NB * ND * 8);
  unsigned* rng = (unsigned*)take((size_t)NSTEP * 2 * 4);
  float* W1T   = (float*)take((size_t)NL * NF * ND * 4);
  float* W2T   = (float*)take((size_t)NL * NF * ND * 4);
  float* WqkvT = (float*)take((size_t)NL * 384 * ND * 4);
  float* WoT   = (float*)take((size_t)NL * ND * ND * 4);
  float* KM = qkv;  // reuse (qkv dead after attention+oln)

  k_rng<<<1, 1, 0, stream>>>(rng);
  // weight transposes (one-time per launch, tiny)
  for (int i = 0; i < NL; ++i) {
    k_tr<<<(NF * ND + 255) / 256, 256, 0, stream>>>(W1 + (size_t)i * NF * ND, W1T + (size_t)i * NF * ND, NF, ND);
    k_tr<<<(NF * ND + 255) / 256, 256, 0, stream>>>(W2 + (size_t)i * ND * NF, W2T + (size_t)i * ND * NF, ND, NF);
    k_tr<<<(384 * ND + 255) / 256, 256, 0, stream>>>(Wqkv + (size_t)i * 384 * ND, WqkvT + (size_t)i * 384 * ND, 384, ND);
    k_tr<<<(ND * ND + 255) / 256, 256, 0, stream>>>(Wo + (size_t)i * ND * ND, WoT + (size_t)i * ND * ND, ND, ND);
  }
  k_embed<<<(NT * ND) / 256, 256, 0, stream>>>(coords, dem, cap, eW, eb, h, dr);
  for (int i = 0; i < NL; ++i) {
    k_qkv<<<NT / QT, 384, 0, stream>>>(h, WqkvT + (size_t)i * 384 * ND, bqkv + (size_t)i * 384, qkv);
    k_attn<<<NB * NH, 256, 0, stream>>>(qkv, att);
    k_oln<<<NT / OT, 128, 0, stream>>>(att, WoT + (size_t)i * ND * ND, bo + (size_t)i * ND,
                                       ln1g + (size_t)i * ND, ln1b + (size_t)i * ND, h);
    k_ffn<<<NT / FT, 256, 0, stream>>>(h, W1T + (size_t)i * NF * ND, b1 + (size_t)i * NF,
                                       W2T + (size_t)i * ND * NF, b2 + (size_t)i * ND,
                                       ln2g + (size_t)i * ND, ln2b + (size_t)i * ND);
  }
  k_gctx<<<NB, 128, 0, stream>>>(h, gctx);
  k_kmat<<<NT, 128, 0, stream>>>(h, Wk, kmat);
  k_prep1<<<1, 128, 0, stream>>>(Wctx, bcap, Wcap, bctx, t1, wu);
  k_M<<<ND, 128, 0, stream>>>(Wq, Wctx, M);
  k_u<<<1, 128, 0, stream>>>(Wq, wu, u);
  k_t2<<<NB, 128, 0, stream>>>(Wctx, gctx, t2);
  k_vb<<<NB, 128, 0, stream>>>(Wq, t2, t1, vb);
  k_c01<<<NT / 256, 256, 0, stream>>>(kmat, vb, u, c0, c1);
  k_KM<<<NT, 128, 0, stream>>>(kmat, M, KM);
  k_P<<<NT, 256, 0, stream>>>(KM, h, P);
  k_decode<<<NB, 256, 0, stream>>>(P, c0, c1, dr, rng, (float*)d_out);
}